// Round 7
// baseline (98.666 us; speedup 1.0000x reference)
//
#include <hip/hip_runtime.h>

#define HDIM 128
#define BDIM 512

typedef __attribute__((ext_vector_type(8))) __bf16 bf16x8;
typedef __attribute__((ext_vector_type(4))) float  f32x4;
typedef __attribute__((ext_vector_type(2))) float  f32x2;

// ---------------- Kernel 1: P = F @ W via bf16 MFMA, K-split x4 waves/tile.
// grid: 512 blocks x 256 thr. bid = net*256 + mtile*8 + ntile.
// Layouts (gfx950 16x16x32_bf16, HW-verified m89/m91):
//   A[m][k]: m = lane&15, k = (lane>>4)*8 + j ; B mirrored ; D: col=lane&15,
//   row=(lane>>4)*4+reg.
__global__ __launch_bounds__(256) void proj_mfma(
    const float* __restrict__ Ft, const float* __restrict__ Fs,
    const float* __restrict__ Wt, const float* __restrict__ Ws,
    __bf16* __restrict__ Pbt, __bf16* __restrict__ Pbs)
{
    const int tid = threadIdx.x;
    const int wv = tid >> 6, l = tid & 63;
    const int t = blockIdx.x;
    const int net = t >> 8;
    const int mtile = (t >> 3) & 31, ntile = t & 7;

    const float* F; const float* W; __bf16* P; int K;
    if (net == 0) { F = Ft; W = Wt; P = Pbt; K = 2048; }
    else          { F = Fs; W = Ws; P = Pbs; K = 768;  }

    const int m0 = mtile * 16, n0 = ntile * 16;
    const int Ks = K >> 2;                 // 512 or 192 (both %32==0)
    const int q = l >> 4, ln = l & 15;
    const int arow = m0 + ln;
    const int bn = n0 + ln;

    f32x4 acc = {0.f, 0.f, 0.f, 0.f};
    for (int k0 = wv * Ks; k0 < (wv + 1) * Ks; k0 += 32) {
        const int ka = k0 + q * 8;
        const float4 fa0 = *(const float4*)&F[(size_t)arow * K + ka];
        const float4 fa1 = *(const float4*)&F[(size_t)arow * K + ka + 4];
        bf16x8 a, b;
        a[0] = (__bf16)fa0.x; a[1] = (__bf16)fa0.y; a[2] = (__bf16)fa0.z; a[3] = (__bf16)fa0.w;
        a[4] = (__bf16)fa1.x; a[5] = (__bf16)fa1.y; a[6] = (__bf16)fa1.z; a[7] = (__bf16)fa1.w;
        #pragma unroll
        for (int j = 0; j < 8; ++j)
            b[j] = (__bf16)W[(size_t)(ka + j) * HDIM + bn];
        acc = __builtin_amdgcn_mfma_f32_16x16x32_bf16(a, b, acc, 0, 0, 0);
    }

    __shared__ float lds[4 * 256];
    #pragma unroll
    for (int r = 0; r < 4; ++r) lds[wv * 256 + r * 64 + l] = acc[r];
    __syncthreads();
    {
        const float s = lds[tid] + lds[256 + tid] + lds[512 + tid] + lds[768 + tid];
        const int r = tid >> 6, l2 = tid & 63;
        const int row = m0 + ((l2 >> 4) << 2) + r;
        const int col = n0 + (l2 & 15);
        P[(size_t)row * HDIM + col] = (__bf16)s;
    }
}

// ---------------- Kernel 2: U/V = Pb @ W1 (+ analytic bias fold) via MFMA.
// grid: 1024 blocks x 64 thr. Outputs stored as bf16 for the pair stage.
// U[i,h] = (P@W1a)[i,h] + c[h],  c = b^T@W1a + b1 (row-independent).
__global__ __launch_bounds__(64) void uv_mfma(
    const __bf16* __restrict__ Pbt, const __bf16* __restrict__ Pbs,
    const float* __restrict__ bt, const float* __restrict__ bs,
    const float* __restrict__ W1, const float* __restrict__ b1,
    __bf16* __restrict__ Ut, __bf16* __restrict__ Vt,
    __bf16* __restrict__ Us, __bf16* __restrict__ Vs,
    float* __restrict__ out)
{
    const int t = blockIdx.x;
    const int net = t >> 9, uvh = (t >> 8) & 1;
    const int mtile = (t >> 3) & 31, ntile = t & 7;
    const int l = threadIdx.x;

    if (t == 0 && l == 0) out[0] = 0.f;   // zero atomic target for pair_kernel

    const __bf16* P   = net ? Pbs : Pbt;
    const float* bias = net ? bs : bt;
    __bf16* O = net ? (uvh ? Vs : Us) : (uvh ? Vt : Ut);
    const float* W1o = W1 + (size_t)uvh * HDIM * HDIM;

    const int m0 = mtile * 16, n0 = ntile * 16;
    const int q = l >> 4, ln = l & 15;
    const int arow = m0 + ln, bn = n0 + ln;

    f32x4 acc = {0.f, 0.f, 0.f, 0.f};
    float cpart = 0.f;
    #pragma unroll
    for (int k0 = 0; k0 < HDIM; k0 += 32) {
        const int ka = k0 + q * 8;
        bf16x8 a = *(const bf16x8*)&P[(size_t)arow * HDIM + ka];
        bf16x8 b;
        #pragma unroll
        for (int j = 0; j < 8; ++j) {
            const float w = W1o[(size_t)(ka + j) * HDIM + bn];
            b[j] = (__bf16)w;
            cpart = fmaf(bias[ka + j], w, cpart);
        }
        acc = __builtin_amdgcn_mfma_f32_16x16x32_bf16(a, b, acc, 0, 0, 0);
    }
    cpart += __shfl_xor(cpart, 16, 64);
    cpart += __shfl_xor(cpart, 32, 64);
    const float cfull = cpart + (uvh == 0 ? b1[bn] : 0.f);

    #pragma unroll
    for (int r = 0; r < 4; ++r) {
        const int row = m0 + q * 4 + r;
        O[(size_t)row * HDIM + bn] = (__bf16)(acc[r] + cfull);
    }
}

// ---------------- Kernel 3: pairwise relations on bf16 U/V tiles.
// grid (16,16) -> 32x32 pair tiles, block (16,16). Thread: 2x2 pairs.
// One ds_read_b128 = 8 h's; full 128-h tile resident (single fill, one sync).
// W2 read via wave-uniform global loads (s_load path, off the LDS pipe).
__device__ __forceinline__ f32x2 bf2up(unsigned d) {
    f32x2 r;
    r.x = __uint_as_float(d << 16);
    r.y = __uint_as_float(d & 0xffff0000u);
    return r;
}

__global__ __launch_bounds__(256) void pair_kernel(
    const __bf16* __restrict__ Ut, const __bf16* __restrict__ Vt,
    const __bf16* __restrict__ Us, const __bf16* __restrict__ Vs,
    const float* __restrict__ W2, const float* __restrict__ b2,
    float* __restrict__ out)
{
    // [net][row*17+h8] ; row stride 17 uint4 (conflict <=2-way, free)
    __shared__ alignas(16) uint4 tU[2][32 * 17];
    __shared__ alignas(16) uint4 tV[2][32 * 17];
    __shared__ float red[256];

    const int tx = threadIdx.x, ty = threadIdx.y;
    const int tid = ty * 16 + tx;
    const int i0 = blockIdx.y * 32, j0 = blockIdx.x * 32;

    const uint4* Ut4 = (const uint4*)Ut;   // row = 16 uint4 (128 bf16)
    const uint4* Vt4 = (const uint4*)Vt;
    const uint4* Us4 = (const uint4*)Us;
    const uint4* Vs4 = (const uint4*)Vs;

    #pragma unroll
    for (int it = 0; it < 2; ++it) {
        int fi = tid + 256 * it;           // 0..511 over 32 rows x 16 chunks
        int r = fi >> 4, c = fi & 15;
        tU[0][r * 17 + c] = Ut4[(size_t)(i0 + r) * 16 + c];
        tU[1][r * 17 + c] = Us4[(size_t)(i0 + r) * 16 + c];
        tV[0][r * 17 + c] = Vt4[(size_t)(j0 + r) * 16 + c];
        tV[1][r * 17 + c] = Vs4[(size_t)(j0 + r) * 16 + c];
    }
    __syncthreads();

    f32x2 aT[2][2] = {{{0.f,0.f},{0.f,0.f}},{{0.f,0.f},{0.f,0.f}}};
    f32x2 aS[2][2] = {{{0.f,0.f},{0.f,0.f}},{{0.f,0.f},{0.f,0.f}}};
    const f32x2 z2 = {0.f, 0.f};

    #pragma unroll 4
    for (int h8 = 0; h8 < 16; ++h8) {
        const uint4 u0 = tU[0][ty * 17 + h8], u1 = tU[0][(ty + 16) * 17 + h8];
        const uint4 v0 = tV[0][tx * 17 + h8], v1 = tV[0][(tx + 16) * 17 + h8];
        const uint4 p0 = tU[1][ty * 17 + h8], p1 = tU[1][(ty + 16) * 17 + h8];
        const uint4 q0 = tV[1][tx * 17 + h8], q1 = tV[1][(tx + 16) * 17 + h8];
        const unsigned ud[2][4] = {{u0.x,u0.y,u0.z,u0.w},{u1.x,u1.y,u1.z,u1.w}};
        const unsigned vd[2][4] = {{v0.x,v0.y,v0.z,v0.w},{v1.x,v1.y,v1.z,v1.w}};
        const unsigned pd[2][4] = {{p0.x,p0.y,p0.z,p0.w},{p1.x,p1.y,p1.z,p1.w}};
        const unsigned qd[2][4] = {{q0.x,q0.y,q0.z,q0.w},{q1.x,q1.y,q1.z,q1.w}};
        #pragma unroll
        for (int c = 0; c < 4; ++c) {
            // wave-uniform -> scalar loads, off the LDS pipe
            const f32x2 w = *(const f32x2*)&W2[h8 * 8 + 2 * c];
            f32x2 U[2], V[2], Pp[2], Q[2];
            #pragma unroll
            for (int a = 0; a < 2; ++a) { U[a] = bf2up(ud[a][c]); Pp[a] = bf2up(pd[a][c]); }
            #pragma unroll
            for (int b = 0; b < 2; ++b) { V[b] = bf2up(vd[b][c]); Q[b] = bf2up(qd[b][c]); }
            #pragma unroll
            for (int a = 0; a < 2; ++a)
                #pragma unroll
                for (int b = 0; b < 2; ++b) {
                    aT[a][b] += __builtin_elementwise_max(U[a] + V[b], z2) * w;
                    aS[a][b] += __builtin_elementwise_max(Pp[a] + Q[b], z2) * w;
                }
        }
    }

    const float b2v = b2[0];
    float local = 0.f;
    #pragma unroll
    for (int a = 0; a < 2; ++a)
        #pragma unroll
        for (int b = 0; b < 2; ++b) {
            int i = i0 + ty + 16 * a;
            int j = j0 + tx + 16 * b;
            if (i != j) {
                float st = aT[a][b].x + aT[a][b].y;
                float ss = aS[a][b].x + aS[a][b].y;
                float tr = 1.f / (1.f + __expf(-(st + b2v)));
                float sr = 1.f / (1.f + __expf(-(ss + b2v)));
                float d = sr - tr;
                local = fmaf(d, d, local);
            }
        }

    red[tid] = local;
    __syncthreads();
    #pragma unroll
    for (int s = 128; s > 0; s >>= 1) {
        if (tid < s) red[tid] += red[tid + s];
        __syncthreads();
    }
    if (tid == 0)
        atomicAdd(out, red[0] * (1.0f / ((float)BDIM * (float)BDIM)));
}

extern "C" void kernel_launch(void* const* d_in, const int* in_sizes, int n_in,
                              void* d_out, int out_size, void* d_ws, size_t ws_size,
                              hipStream_t stream) {
    const float* teacher = (const float*)d_in[0];   // [512,2048]
    const float* student = (const float*)d_in[1];   // [512,768]
    const float* Wt = (const float*)d_in[2];        // [2048,128]
    const float* bt = (const float*)d_in[3];        // [128]
    const float* Ws = (const float*)d_in[4];        // [768,128]
    const float* bs = (const float*)d_in[5];        // [128]
    const float* W1 = (const float*)d_in[6];        // [256,128]
    const float* b1 = (const float*)d_in[7];        // [128]
    const float* W2 = (const float*)d_in[8];        // [128,1]
    const float* b2 = (const float*)d_in[9];        // [1]
    float* out = (float*)d_out;

    const size_t M = (size_t)BDIM * HDIM;           // 65536 elements
    __bf16* Pbt = (__bf16*)d_ws;                    // bf16 [512][128] each
    __bf16* Pbs = Pbt + M;
    __bf16* Ut  = Pbs + M;
    __bf16* Vt  = Ut + M;
    __bf16* Us  = Vt + M;
    __bf16* Vs  = Us + M;

    proj_mfma<<<512, 256, 0, stream>>>(teacher, student, Wt, Ws, Pbt, Pbs);

    uv_mfma<<<1024, 64, 0, stream>>>(Pbt, Pbs, bt, bs, W1, b1,
                                     Ut, Vt, Us, Vs, out);

    pair_kernel<<<dim3(16, 16), dim3(16, 16), 0, stream>>>(
        Ut, Vt, Us, Vs, W2, b2, out);
}